// Round 6
// baseline (34.620 us; speedup 1.0000x reference)
//
#include <hip/hip_runtime.h>

// out[z, k] = sum_{n in segment(k)} vals[n] * x1[z, i_idx[n]] * x2[z, j_idx[n]]
//
// Structure facts (from the reference generator _build_sparse_tp):
//  * entries are ordered so that every output row k is ONE contiguous run in n
//    -- runs are in generator path order, NOT ascending k. Bounds live in
//       per-k seg_start/seg_end (row_ptr CSR is WRONG — R4 failure).
//  * every k in [0, dim_out) appears => boundary detection fully populates
//    both arrays, no memset needed (verified R3/R5).
//
// R6: phase-serialization fix — persistent blocks iterate 4 z-groups with
// DOUBLE-BUFFERED LDS and one barrier/iter, so the store burst of group g
// drains under the stage+gather of group g+1. ZPT=16, STRIDE=20 (16B-aligned
// ds_read_b128; start bank group = 4*((5i+q) mod 8) covers all 8 quad-groups).

#define ZPT 16
#define BLK 512
#define DIM_IN 144
#define STRIDE 20
#define NZG 64          // 1024 / ZPT z-groups
#define GRID_Y 16       // each block handles NZG/GRID_Y = 4 groups

__global__ void prep_kernel(const int* __restrict__ k_idx,
                            const float* __restrict__ vals,
                            const int* __restrict__ i_idx,
                            const int* __restrict__ j_idx,
                            int nnz,
                            int* __restrict__ seg_start,
                            int* __restrict__ seg_end,
                            int2* __restrict__ packed) {
    int n = blockIdx.x * blockDim.x + threadIdx.x;
    if (n >= nnz) return;
    int k = k_idx[n];
    if (n == 0 || k_idx[n - 1] != k) seg_start[k] = n;
    if (n == nnz - 1 || k_idx[n + 1] != k) seg_end[k] = n + 1;
    packed[n] = make_int2(i_idx[n] | (j_idx[n] << 16), __float_as_int(vals[n]));
}

__global__ __launch_bounds__(BLK) void tp_kernel(
        const float* __restrict__ x1,
        const float* __restrict__ x2,
        const int2* __restrict__ packed,
        const int* __restrict__ seg_start,
        const int* __restrict__ seg_end,
        float* __restrict__ out,
        int dim_out) {
    __shared__ __align__(16) float x1s[2][DIM_IN * STRIDE];
    __shared__ __align__(16) float x2s[2][DIM_IN * STRIDE];

    const int k = blockIdx.x * BLK + threadIdx.x;
    const bool live = (k < dim_out);

    int s = 0, e = 0;
    if (live) {
        s = seg_start[k];
        e = seg_end[k];
    }

    int p = 0;
    for (int g = blockIdx.y; g < NZG; g += GRID_Y, p ^= 1) {
        const int z0 = g * ZPT;

        // stage transposed into buffer p: x?s[p][i*STRIDE + t] = x?[(z0+t)*DIM_IN + i]
        for (int idx = threadIdx.x; idx < ZPT * (DIM_IN / 4); idx += BLK) {
            const int t  = idx / (DIM_IN / 4);
            const int i4 = idx % (DIM_IN / 4);
            const float4 a = *(const float4*)(x1 + (size_t)(z0 + t) * DIM_IN + i4 * 4);
            const float4 b = *(const float4*)(x2 + (size_t)(z0 + t) * DIM_IN + i4 * 4);
            const int base = i4 * 4 * STRIDE + t;
            float* d1 = x1s[p];
            float* d2 = x2s[p];
            d1[base             ] = a.x;
            d1[base +     STRIDE] = a.y;
            d1[base + 2 * STRIDE] = a.z;
            d1[base + 3 * STRIDE] = a.w;
            d2[base             ] = b.x;
            d2[base +     STRIDE] = b.y;
            d2[base + 2 * STRIDE] = b.z;
            d2[base + 3 * STRIDE] = b.w;
        }
        __syncthreads();
        // safety of single barrier: gather(g) reads buf p; next stage writes
        // buf p^1 (disjoint); stage of p again (g+2) happens only after the
        // g+1 barrier, which every thread reaches only after its gather(g).

        if (live) {
            float acc[ZPT];
#pragma unroll
            for (int t = 0; t < ZPT; ++t) acc[t] = 0.0f;

            // software-pipelined entry loop over this k's segment
            int n = s;
            if (n < e) {
                int2 ev = packed[n];
                const float* b1 = x1s[p];
                const float* b2 = x2s[p];
                for (;;) {
                    const bool more = (n + 1 < e);
                    int2 evn;
                    if (more) evn = packed[n + 1];

                    const float c = __int_as_float(ev.y);
                    const int i = ev.x & 0xffff;
                    const int j = ev.x >> 16;
                    const float4* p1 = (const float4*)(b1 + i * STRIDE);
                    const float4* p2 = (const float4*)(b2 + j * STRIDE);
#pragma unroll
                    for (int q = 0; q < ZPT / 4; ++q) {
                        const float4 a = p1[q];
                        const float4 b = p2[q];
                        acc[4 * q + 0] += c * a.x * b.x;
                        acc[4 * q + 1] += c * a.y * b.y;
                        acc[4 * q + 2] += c * a.z * b.z;
                        acc[4 * q + 3] += c * a.w * b.w;
                    }

                    ++n;
                    if (!more) break;
                    ev = evn;
                }
            }

            // coalesced stores; these drain while the next iteration stages
#pragma unroll
            for (int t = 0; t < ZPT; ++t) {
                out[(size_t)(z0 + t) * dim_out + k] = acc[t];
            }
        }
    }
}

extern "C" void kernel_launch(void* const* d_in, const int* in_sizes, int n_in,
                              void* d_out, int out_size, void* d_ws, size_t ws_size,
                              hipStream_t stream) {
    const float* x1   = (const float*)d_in[0];
    const float* x2   = (const float*)d_in[1];
    const float* vals = (const float*)d_in[2];
    const int*   kidx = (const int*)d_in[3];
    const int*   iidx = (const int*)d_in[4];
    const int*   jidx = (const int*)d_in[5];
    float* out = (float*)d_out;

    const int n_batch = 1024;                  // N_BATCH in the reference
    const int dim_out = out_size / n_batch;    // 20736
    const int nnz     = in_sizes[2];

    // workspace: seg_start[dim_out], seg_end[dim_out], packed int2[nnz]
    int*  seg_start = (int*)d_ws;
    int*  seg_end   = seg_start + dim_out;
    int2* packed    = (int2*)(seg_end + dim_out);   // 8B-aligned

    {
        int grid = (nnz + 255) / 256;
        prep_kernel<<<grid, 256, 0, stream>>>(kidx, vals, iidx, jidx, nnz,
                                              seg_start, seg_end, packed);
    }

    {
        dim3 grid((dim_out + BLK - 1) / BLK, GRID_Y);
        tp_kernel<<<grid, BLK, 0, stream>>>(x1, x2, packed,
                                            seg_start, seg_end, out, dim_out);
    }
}